// Round 3
// baseline (1417.496 us; speedup 1.0000x reference)
//
#include <hip/hip_runtime.h>
#include <hip/hip_bf16.h>

// LSTM: T=2048, B=512, INPUT=42, HIDDEN=64. Output uses ONLY batch element 511
// (reference indexes lstm_out[:, -1, :]). So we compute the recurrence for a
// single batch row: 2048 sequential steps of a 256x64 matvec + activations.
//
// Scan kernel: 1 block, 256 threads = 64 units x 4 k-chunks.
// lane = u*4 + kc. Each lane: partial gate sums {i,f,g,o} of unit u over
// k in [16kc,16kc+16); weights held in 16 named float4 REGISTERS (round-1
// lesson: float[16] arrays + default launch_bounds spilled to scratch ->
// VGPR_Count=48 and ~3x slowdown). __launch_bounds__(256,1) lifts the cap.
// Round-2 lesson: FMA4 as a macro with param `w` self-captured the `.w`
// member access -> use an inline function, never a macro, for this.

#define T_STEPS 2048
#define BATCH   512
#define NIN     42
#define NH      64
#define NG      256   // 4*NH

// ---------------- Kernel 1: input projection for batch row 511 ----------------
__global__ __launch_bounds__(256) void xproj_kernel(
    const float* __restrict__ x, const float* __restrict__ W_ih,
    const float* __restrict__ b_ih, const float* __restrict__ b_hh,
    float* __restrict__ xp)
{
    const int t = blockIdx.x;
    const int g = threadIdx.x;           // 0..255
    __shared__ float xs[NIN];
    const float* xrow = x + ((size_t)t * BATCH + (BATCH - 1)) * NIN;
    if (threadIdx.x < NIN) xs[threadIdx.x] = xrow[threadIdx.x];
    __syncthreads();
    const float* wr = W_ih + g * NIN;
    float s = b_ih[g] + b_hh[g];
#pragma unroll
    for (int i = 0; i < NIN; ++i) s += wr[i] * xs[i];
    xp[t * NG + g] = s;
}

// ---------------- Kernel 2: sequential LSTM scan (1 block, 256 threads) -------
__device__ __forceinline__ float fma4(float acc, float4 a, float4 b) {
    acc = fmaf(a.x, b.x, acc);
    acc = fmaf(a.y, b.y, acc);
    acc = fmaf(a.z, b.z, acc);
    acc = fmaf(a.w, b.w, acc);
    return acc;
}

__global__ __launch_bounds__(256, 1) void lstm_scan_kernel(
    const float* __restrict__ W_hh, const float* __restrict__ xp,
    float* __restrict__ hout)
{
    const int lane = threadIdx.x;       // 0..255
    const int kc   = lane & 3;          // k-chunk (also: which gate's xp I seed)
    const int u    = lane >> 2;         // hidden unit

    __shared__ __align__(16) float hbuf[2][NH];
    if (lane < NH) { hbuf[0][lane] = 0.f; hbuf[1][lane] = 0.f; }

    // Weights in named float4 registers: 16 float4 = 64 VGPRs.
    const float4* W0 = (const float4*)(W_hh + (0 * NH + u) * NH + kc * 16);
    const float4* W1 = (const float4*)(W_hh + (1 * NH + u) * NH + kc * 16);
    const float4* W2 = (const float4*)(W_hh + (2 * NH + u) * NH + kc * 16);
    const float4* W3 = (const float4*)(W_hh + (3 * NH + u) * NH + kc * 16);
    float4 w00 = W0[0], w01 = W0[1], w02 = W0[2], w03 = W0[3];
    float4 w10 = W1[0], w11 = W1[1], w12 = W1[2], w13 = W1[3];
    float4 w20 = W2[0], w21 = W2[1], w22 = W2[2], w23 = W2[3];
    float4 w30 = W3[0], w31 = W3[1], w32 = W3[2], w33 = W3[3];

    float c = 0.f;
    // Seed: lane (u,kc) carries gate kc's xp contribution -> 1 uniform load/lane.
    float seed = xp[kc * NH + u];   // t = 0
    __syncthreads();

    int p = 0;
    for (int t = 0; t < T_STEPS; ++t) {
        const float4* hb = (const float4*)hbuf[p];
        float4 hv0 = hb[kc * 4 + 0];
        float4 hv1 = hb[kc * 4 + 1];
        float4 hv2 = hb[kc * 4 + 2];
        float4 hv3 = hb[kc * 4 + 3];

        float s0 = (kc == 0) ? seed : 0.f;
        float s1 = (kc == 1) ? seed : 0.f;
        float s2 = (kc == 2) ? seed : 0.f;
        float s3 = (kc == 3) ? seed : 0.f;

        // prefetch next step's seed (hidden under the FMA block)
        if (t + 1 < T_STEPS) seed = xp[(size_t)(t + 1) * NG + kc * NH + u];

        s0 = fma4(s0, w00, hv0); s0 = fma4(s0, w01, hv1);
        s0 = fma4(s0, w02, hv2); s0 = fma4(s0, w03, hv3);
        s1 = fma4(s1, w10, hv0); s1 = fma4(s1, w11, hv1);
        s1 = fma4(s1, w12, hv2); s1 = fma4(s1, w13, hv3);
        s2 = fma4(s2, w20, hv0); s2 = fma4(s2, w21, hv1);
        s2 = fma4(s2, w22, hv2); s2 = fma4(s2, w23, hv3);
        s3 = fma4(s3, w30, hv0); s3 = fma4(s3, w31, hv1);
        s3 = fma4(s3, w32, hv2); s3 = fma4(s3, w33, hv3);

        // butterfly over the 4 k-chunks (lanes u*4 .. u*4+3)
        s0 += __shfl_xor(s0, 1); s1 += __shfl_xor(s1, 1);
        s2 += __shfl_xor(s2, 1); s3 += __shfl_xor(s3, 1);
        s0 += __shfl_xor(s0, 2); s1 += __shfl_xor(s1, 2);
        s2 += __shfl_xor(s2, 2); s3 += __shfl_xor(s3, 2);

        // activations: gate order i, f, g, o
        float i_ = 1.f / (1.f + __expf(-s0));
        float f_ = 1.f / (1.f + __expf(-s1));
        float g_ = 1.f - 2.f / (1.f + __expf(2.f * s2));   // tanh
        float o_ = 1.f / (1.f + __expf(-s3));

        c = f_ * c + i_ * g_;
        float th = 1.f - 2.f / (1.f + __expf(2.f * c));    // tanh(c)
        float hn = o_ * th;

        if (kc == 0) {
            hbuf[1 - p][u] = hn;          // double buffer: one barrier/step
            hout[(size_t)t * NH + u] = hn;
        }
        __syncthreads();
        p ^= 1;
    }
}

// ---------------- Kernel 3: output projection out[t] = W_out @ h_t + b_out ----
__global__ __launch_bounds__(256) void outproj_kernel(
    const float* __restrict__ hout, const float* __restrict__ W_out,
    const float* __restrict__ b_out, float* __restrict__ out)
{
    int idx = blockIdx.x * blockDim.x + threadIdx.x;   // T*2
    if (idx >= T_STEPS * 2) return;
    int t = idx >> 1, o = idx & 1;
    const float* hr = hout + (size_t)t * NH;
    const float* wr = W_out + o * NH;
    float s = b_out[o];
#pragma unroll
    for (int j = 0; j < NH; ++j) s += hr[j] * wr[j];
    out[t * 2 + o] = s;
}

extern "C" void kernel_launch(void* const* d_in, const int* in_sizes, int n_in,
                              void* d_out, int out_size, void* d_ws, size_t ws_size,
                              hipStream_t stream) {
    const float* x     = (const float*)d_in[0];
    const float* W_ih  = (const float*)d_in[1];
    const float* W_hh  = (const float*)d_in[2];
    const float* b_ih  = (const float*)d_in[3];
    const float* b_hh  = (const float*)d_in[4];
    const float* W_out = (const float*)d_in[5];
    const float* b_out = (const float*)d_in[6];
    float* out = (float*)d_out;

    // workspace layout: xp (T*256 floats) | hout (T*64 floats)  = 2.5 MB
    float* xp   = (float*)d_ws;
    float* hout = xp + (size_t)T_STEPS * NG;

    xproj_kernel<<<T_STEPS, 256, 0, stream>>>(x, W_ih, b_ih, b_hh, xp);
    lstm_scan_kernel<<<1, 256, 0, stream>>>(W_hh, xp, hout);
    outproj_kernel<<<(T_STEPS * 2 + 255) / 256, 256, 0, stream>>>(hout, W_out, b_out, out);
}

// Round 4
// 1209.379 us; speedup vs baseline: 1.1721x; 1.1721x over previous
//
#include <hip/hip_runtime.h>
#include <hip/hip_bf16.h>

// LSTM: T=2048, B=512, INPUT=42, HIDDEN=64. Output uses ONLY batch element 511
// (reference indexes lstm_out[:, -1, :]). So: single-row recurrence, 2048
// sequential steps of a 256x64 matvec + activations, on ONE block.
//
// Round-3 lesson: VGPR_Count=44 proved the compiler SANK the weight loads into
// the loop (legal: const __restrict__ + no memory clobber in loop), and
// __syncthreads() emits s_waitcnt vmcnt(0) before s_barrier -> every step paid
// an L2 drain. Fix: lgkmcnt-only asm barrier (memory clobber also forces
// weights to stay hoisted in registers), xp seeds prefetched to registers per
// 8-step chunk, hout staged in LDS and flushed with never-awaited stores.

#define T_STEPS 2048
#define BATCH   512
#define NIN     42
#define NH      64
#define NG      256   // 4*NH
#define CH      8     // steps per chunk
#define NCHUNK  (T_STEPS / CH)

// ---------------- Kernel 1: input projection for batch row 511 ----------------
__global__ __launch_bounds__(256) void xproj_kernel(
    const float* __restrict__ x, const float* __restrict__ W_ih,
    const float* __restrict__ b_ih, const float* __restrict__ b_hh,
    float* __restrict__ xp)
{
    const int t = blockIdx.x;
    const int g = threadIdx.x;           // 0..255
    __shared__ float xs[NIN];
    const float* xrow = x + ((size_t)t * BATCH + (BATCH - 1)) * NIN;
    if (threadIdx.x < NIN) xs[threadIdx.x] = xrow[threadIdx.x];
    __syncthreads();
    const float* wr = W_ih + g * NIN;
    float s = b_ih[g] + b_hh[g];
#pragma unroll
    for (int i = 0; i < NIN; ++i) s += wr[i] * xs[i];
    xp[t * NG + g] = s;
}

// ---------------- Kernel 2: sequential LSTM scan (1 block, 256 threads) -------
__device__ __forceinline__ float fma4(float acc, float4 a, float4 b) {
    acc = fmaf(a.x, b.x, acc);
    acc = fmaf(a.y, b.y, acc);
    acc = fmaf(a.z, b.z, acc);
    acc = fmaf(a.w, b.w, acc);
    return acc;
}

// Workgroup barrier that drains ONLY LDS ops (lgkmcnt), leaving global
// loads/stores in flight. The "memory" clobber also prevents the compiler
// from rematerializing const loads inside the loop.
__device__ __forceinline__ void wg_barrier_lgkm() {
    asm volatile("s_waitcnt lgkmcnt(0)\n\ts_barrier" ::: "memory");
}

__device__ __forceinline__ void pin4(float4& v) {
    asm volatile("" : "+v"(v.x), "+v"(v.y), "+v"(v.z), "+v"(v.w));
}

__device__ __forceinline__ float sigmoid_f(float x) {
    return __builtin_amdgcn_rcpf(1.f + __expf(-x));
}
__device__ __forceinline__ float tanh_f(float x) {
    return 1.f - 2.f * __builtin_amdgcn_rcpf(1.f + __expf(2.f * x));
}

__global__ __launch_bounds__(256, 1) void lstm_scan_kernel(
    const float* __restrict__ W_hh, const float* __restrict__ xp,
    float* __restrict__ hout)
{
    const int lane = threadIdx.x;       // 0..255
    const int kc   = lane & 3;          // k-chunk (also: which gate's xp I seed)
    const int u    = lane >> 2;         // hidden unit

    __shared__ __align__(16) float hbuf[2][NH];        // h exchange (double buf)
    __shared__ __align__(16) float hstage[2][CH][NH];  // hout staging
    if (lane < NH) { hbuf[0][lane] = 0.f; hbuf[1][lane] = 0.f; }

    // Weights: W_hh[gate*64+u][kc*16 .. +16) -> 16 float4 = 64 VGPRs, pinned.
    const float4* W0 = (const float4*)(W_hh + (0 * NH + u) * NH + kc * 16);
    const float4* W1 = (const float4*)(W_hh + (1 * NH + u) * NH + kc * 16);
    const float4* W2 = (const float4*)(W_hh + (2 * NH + u) * NH + kc * 16);
    const float4* W3 = (const float4*)(W_hh + (3 * NH + u) * NH + kc * 16);
    float4 w00 = W0[0], w01 = W0[1], w02 = W0[2], w03 = W0[3];
    float4 w10 = W1[0], w11 = W1[1], w12 = W1[2], w13 = W1[3];
    float4 w20 = W2[0], w21 = W2[1], w22 = W2[2], w23 = W2[3];
    float4 w30 = W3[0], w31 = W3[1], w32 = W3[2], w33 = W3[3];
    pin4(w00); pin4(w01); pin4(w02); pin4(w03);
    pin4(w10); pin4(w11); pin4(w12); pin4(w13);
    pin4(w20); pin4(w21); pin4(w22); pin4(w23);
    pin4(w30); pin4(w31); pin4(w32); pin4(w33);

    float c = 0.f;
    const int seed_off = kc * NH + u;   // my xp column

    // Prefetch chunk 0's seeds into registers.
    float xq[CH];
#pragma unroll
    for (int tt = 0; tt < CH; ++tt) xq[tt] = xp[tt * NG + seed_off];

    wg_barrier_lgkm();                  // hbuf zeros visible

    for (int ch = 0; ch < NCHUNK; ++ch) {
        // Prefetch next chunk's seeds (consumed one chunk later; vmcnt wait
        // lands ~8 steps after issue -> no stall).
        float xn[CH];
        if (ch + 1 < NCHUNK) {
#pragma unroll
            for (int tt = 0; tt < CH; ++tt)
                xn[tt] = xp[(size_t)(ch + 1) * (CH * NG) + tt * NG + seed_off];
        }

#pragma unroll
        for (int tt = 0; tt < CH; ++tt) {
            const int p = tt & 1;
            const float4* hb = (const float4*)hbuf[p];
            float4 hv0 = hb[kc * 4 + 0];
            float4 hv1 = hb[kc * 4 + 1];
            float4 hv2 = hb[kc * 4 + 2];
            float4 hv3 = hb[kc * 4 + 3];

            float s0 = (kc == 0) ? xq[tt] : 0.f;
            float s1 = (kc == 1) ? xq[tt] : 0.f;
            float s2 = (kc == 2) ? xq[tt] : 0.f;
            float s3 = (kc == 3) ? xq[tt] : 0.f;

            s0 = fma4(s0, w00, hv0); s0 = fma4(s0, w01, hv1);
            s0 = fma4(s0, w02, hv2); s0 = fma4(s0, w03, hv3);
            s1 = fma4(s1, w10, hv0); s1 = fma4(s1, w11, hv1);
            s1 = fma4(s1, w12, hv2); s1 = fma4(s1, w13, hv3);
            s2 = fma4(s2, w20, hv0); s2 = fma4(s2, w21, hv1);
            s2 = fma4(s2, w22, hv2); s2 = fma4(s2, w23, hv3);
            s3 = fma4(s3, w30, hv0); s3 = fma4(s3, w31, hv1);
            s3 = fma4(s3, w32, hv2); s3 = fma4(s3, w33, hv3);

            // butterfly over the 4 k-chunks (lanes u*4 .. u*4+3)
            s0 += __shfl_xor(s0, 1); s1 += __shfl_xor(s1, 1);
            s2 += __shfl_xor(s2, 1); s3 += __shfl_xor(s3, 1);
            s0 += __shfl_xor(s0, 2); s1 += __shfl_xor(s1, 2);
            s2 += __shfl_xor(s2, 2); s3 += __shfl_xor(s3, 2);

            // gates i, f, g, o
            float i_ = sigmoid_f(s0);
            float f_ = sigmoid_f(s1);
            float g_ = tanh_f(s2);
            float o_ = sigmoid_f(s3);

            c = f_ * c + i_ * g_;
            float hn = o_ * tanh_f(c);

            if (kc == 0) {
                hbuf[1 - p][u] = hn;
                hstage[ch & 1][tt][u] = hn;
            }
            wg_barrier_lgkm();
        }

        // Flush this chunk's h values: 8*64 = 512 floats, coalesced dwordx4,
        // never awaited (stores ride across lgkm-only barriers).
        if (lane < 128) {
            const float4 hv = *(const float4*)(&hstage[ch & 1][0][0] + lane * 4);
            *(float4*)(hout + (size_t)ch * (CH * NH) + lane * 4) = hv;
        }

#pragma unroll
        for (int tt = 0; tt < CH; ++tt) xq[tt] = xn[tt];
    }
}

// ---------------- Kernel 3: output projection out[t] = W_out @ h_t + b_out ----
__global__ __launch_bounds__(256) void outproj_kernel(
    const float* __restrict__ hout, const float* __restrict__ W_out,
    const float* __restrict__ b_out, float* __restrict__ out)
{
    int idx = blockIdx.x * blockDim.x + threadIdx.x;   // T*2
    if (idx >= T_STEPS * 2) return;
    int t = idx >> 1, o = idx & 1;
    const float* hr = hout + (size_t)t * NH;
    const float* wr = W_out + o * NH;
    float s = b_out[o];
#pragma unroll
    for (int j = 0; j < NH; ++j) s += hr[j] * wr[j];
    out[t * 2 + o] = s;
}

extern "C" void kernel_launch(void* const* d_in, const int* in_sizes, int n_in,
                              void* d_out, int out_size, void* d_ws, size_t ws_size,
                              hipStream_t stream) {
    const float* x     = (const float*)d_in[0];
    const float* W_ih  = (const float*)d_in[1];
    const float* W_hh  = (const float*)d_in[2];
    const float* b_ih  = (const float*)d_in[3];
    const float* b_hh  = (const float*)d_in[4];
    const float* W_out = (const float*)d_in[5];
    const float* b_out = (const float*)d_in[6];
    float* out = (float*)d_out;

    // workspace layout: xp (T*256 floats) | hout (T*64 floats)  = 2.5 MB
    float* xp   = (float*)d_ws;
    float* hout = xp + (size_t)T_STEPS * NG;

    xproj_kernel<<<T_STEPS, 256, 0, stream>>>(x, W_ih, b_ih, b_hh, xp);
    lstm_scan_kernel<<<1, 256, 0, stream>>>(W_hh, xp, hout);
    outproj_kernel<<<(T_STEPS * 2 + 255) / 256, 256, 0, stream>>>(hout, W_out, b_out, out);
}

// Round 5
// 1119.350 us; speedup vs baseline: 1.2664x; 1.0804x over previous
//
#include <hip/hip_runtime.h>
#include <hip/hip_bf16.h>

// LSTM: T=2048, B=512, INPUT=42, HIDDEN=64. Output uses ONLY batch element 511
// (reference indexes lstm_out[:, -1, :]). Single-row recurrence: 2048
// sequential steps of a 256x64 matvec + activations on ONE block.
//
// Round-3: compiler sank weight loads into the loop (remat), VGPR=44.
// Round-4: "memory" clobber blocked remat -> RA spilled the 64 weight floats
//   to scratch instead (VGPR=52); 16KB/step scratch reload from L2 at
//   ~56B/cyc/CU = ~1170 cyc/step == measured. Root cause: scheduler/RA chases
//   its default occupancy target; __launch_bounds__ only sets a floor.
// Fix: amdgpu_waves_per_eu(1,1) -> occupancy target = 1 wave/EU (our exact
//   shape: 4 waves on 4 SIMDs) -> no motive to spill or sink.

#define T_STEPS 2048
#define BATCH   512
#define NIN     42
#define NH      64
#define NG      256   // 4*NH
#define CH      8     // scan steps per chunk
#define NCHUNK  (T_STEPS / CH)
#define XT      16    // timesteps per xproj block

// ---------------- Kernel 1: input projection for batch row 511 ----------------
// Each block handles XT timesteps; W_ih staged in LDS once per block.
__global__ __launch_bounds__(256) void xproj_kernel(
    const float* __restrict__ x, const float* __restrict__ W_ih,
    const float* __restrict__ b_ih, const float* __restrict__ b_hh,
    float* __restrict__ xp)
{
    const int g  = threadIdx.x;          // gate row 0..255
    const int t0 = blockIdx.x * XT;
    __shared__ float ws[NG * NIN];       // W_ih rows, packed [g][42]
    __shared__ float xs[XT][NIN];
    // cooperative load of W_ih (256*42 floats, 42 per thread, coalesced-ish)
    for (int i = threadIdx.x; i < NG * NIN; i += 256) ws[i] = W_ih[i];
    for (int i = threadIdx.x; i < XT * NIN; i += 256) {
        int tt = i / NIN, j = i % NIN;
        xs[tt][j] = x[((size_t)(t0 + tt) * BATCH + (BATCH - 1)) * NIN + j];
    }
    const float bias = b_ih[g] + b_hh[g];
    __syncthreads();
    const float* wr = &ws[g * NIN];
    for (int tt = 0; tt < XT; ++tt) {
        float s = bias;
#pragma unroll
        for (int i = 0; i < NIN; ++i) s += wr[i] * xs[tt][i];
        xp[(size_t)(t0 + tt) * NG + g] = s;
    }
}

// ---------------- Kernel 2: sequential LSTM scan (1 block, 256 threads) -------
__device__ __forceinline__ float fma4(float acc, float4 a, float4 b) {
    acc = fmaf(a.x, b.x, acc);
    acc = fmaf(a.y, b.y, acc);
    acc = fmaf(a.z, b.z, acc);
    acc = fmaf(a.w, b.w, acc);
    return acc;
}

// Barrier draining ONLY LDS ops (lgkmcnt); global loads/stores stay in flight.
__device__ __forceinline__ void wg_barrier_lgkm() {
    asm volatile("s_waitcnt lgkmcnt(0)\n\ts_barrier" ::: "memory");
}

__device__ __forceinline__ void pin4(float4& v) {
    asm volatile("" : "+v"(v.x), "+v"(v.y), "+v"(v.z), "+v"(v.w));
}

__device__ __forceinline__ float sigmoid_f(float x) {
    return __builtin_amdgcn_rcpf(1.f + __expf(-x));
}
__device__ __forceinline__ float tanh_f(float x) {
    return 1.f - 2.f * __builtin_amdgcn_rcpf(1.f + __expf(2.f * x));
}

__global__ void
__attribute__((amdgpu_flat_work_group_size(256, 256), amdgpu_waves_per_eu(1, 1)))
lstm_scan_kernel(
    const float* __restrict__ W_hh, const float* __restrict__ xp,
    float* __restrict__ hout)
{
    const int lane = threadIdx.x;       // 0..255
    const int kc   = lane & 3;          // k-chunk (also: which gate's xp I seed)
    const int u    = lane >> 2;         // hidden unit

    __shared__ __align__(16) float hbuf[2][NH];        // h exchange (double buf)
    __shared__ __align__(16) float hstage[2][CH][NH];  // hout staging
    if (lane < NH) { hbuf[0][lane] = 0.f; hbuf[1][lane] = 0.f; }

    // Weights: W_hh[gate*64+u][kc*16 .. +16) -> 16 float4 = 64 VGPRs, pinned.
    const float4* W0 = (const float4*)(W_hh + (0 * NH + u) * NH + kc * 16);
    const float4* W1 = (const float4*)(W_hh + (1 * NH + u) * NH + kc * 16);
    const float4* W2 = (const float4*)(W_hh + (2 * NH + u) * NH + kc * 16);
    const float4* W3 = (const float4*)(W_hh + (3 * NH + u) * NH + kc * 16);
    float4 w00 = W0[0], w01 = W0[1], w02 = W0[2], w03 = W0[3];
    float4 w10 = W1[0], w11 = W1[1], w12 = W1[2], w13 = W1[3];
    float4 w20 = W2[0], w21 = W2[1], w22 = W2[2], w23 = W2[3];
    float4 w30 = W3[0], w31 = W3[1], w32 = W3[2], w33 = W3[3];
    pin4(w00); pin4(w01); pin4(w02); pin4(w03);
    pin4(w10); pin4(w11); pin4(w12); pin4(w13);
    pin4(w20); pin4(w21); pin4(w22); pin4(w23);
    pin4(w30); pin4(w31); pin4(w32); pin4(w33);

    float c = 0.f;
    const int seed_off = kc * NH + u;   // my xp column

    // Prefetch chunk 0's seeds into registers.
    float xq[CH];
#pragma unroll
    for (int tt = 0; tt < CH; ++tt) xq[tt] = xp[tt * NG + seed_off];

    wg_barrier_lgkm();                  // hbuf zeros visible

    for (int ch = 0; ch < NCHUNK; ++ch) {
        // Prefetch next chunk's seeds (consumed one chunk later).
        float xn[CH];
        if (ch + 1 < NCHUNK) {
#pragma unroll
            for (int tt = 0; tt < CH; ++tt)
                xn[tt] = xp[(size_t)(ch + 1) * (CH * NG) + tt * NG + seed_off];
        }

#pragma unroll
        for (int tt = 0; tt < CH; ++tt) {
            const int p = tt & 1;
            const float4* hb = (const float4*)hbuf[p];
            float4 hv0 = hb[kc * 4 + 0];
            float4 hv1 = hb[kc * 4 + 1];
            float4 hv2 = hb[kc * 4 + 2];
            float4 hv3 = hb[kc * 4 + 3];

            float s0 = (kc == 0) ? xq[tt] : 0.f;
            float s1 = (kc == 1) ? xq[tt] : 0.f;
            float s2 = (kc == 2) ? xq[tt] : 0.f;
            float s3 = (kc == 3) ? xq[tt] : 0.f;

            s0 = fma4(s0, w00, hv0); s0 = fma4(s0, w01, hv1);
            s0 = fma4(s0, w02, hv2); s0 = fma4(s0, w03, hv3);
            s1 = fma4(s1, w10, hv0); s1 = fma4(s1, w11, hv1);
            s1 = fma4(s1, w12, hv2); s1 = fma4(s1, w13, hv3);
            s2 = fma4(s2, w20, hv0); s2 = fma4(s2, w21, hv1);
            s2 = fma4(s2, w22, hv2); s2 = fma4(s2, w23, hv3);
            s3 = fma4(s3, w30, hv0); s3 = fma4(s3, w31, hv1);
            s3 = fma4(s3, w32, hv2); s3 = fma4(s3, w33, hv3);

            // butterfly over the 4 k-chunks (intra-quad -> DPP, cheap)
            s0 += __shfl_xor(s0, 1); s1 += __shfl_xor(s1, 1);
            s2 += __shfl_xor(s2, 1); s3 += __shfl_xor(s3, 1);
            s0 += __shfl_xor(s0, 2); s1 += __shfl_xor(s1, 2);
            s2 += __shfl_xor(s2, 2); s3 += __shfl_xor(s3, 2);

            // gates i, f, g, o
            float i_ = sigmoid_f(s0);
            float f_ = sigmoid_f(s1);
            float g_ = tanh_f(s2);
            float o_ = sigmoid_f(s3);

            c = f_ * c + i_ * g_;
            float hn = o_ * tanh_f(c);

            if (kc == 0) {
                hbuf[1 - p][u] = hn;
                hstage[ch & 1][tt][u] = hn;
            }
            wg_barrier_lgkm();
        }

        // Flush chunk's h (8*64 floats), coalesced dwordx4, never awaited.
        if (lane < 128) {
            const float4 hv = *(const float4*)(&hstage[ch & 1][0][0] + lane * 4);
            *(float4*)(hout + (size_t)ch * (CH * NH) + lane * 4) = hv;
        }

#pragma unroll
        for (int tt = 0; tt < CH; ++tt) xq[tt] = xn[tt];
    }
}

// ---------------- Kernel 3: output projection out[t] = W_out @ h_t + b_out ----
__global__ __launch_bounds__(256) void outproj_kernel(
    const float* __restrict__ hout, const float* __restrict__ W_out,
    const float* __restrict__ b_out, float* __restrict__ out)
{
    int idx = blockIdx.x * blockDim.x + threadIdx.x;   // T*2
    if (idx >= T_STEPS * 2) return;
    int t = idx >> 1, o = idx & 1;
    const float* hr = hout + (size_t)t * NH;
    const float* wr = W_out + o * NH;
    float s = b_out[o];
#pragma unroll
    for (int j = 0; j < NH; ++j) s += hr[j] * wr[j];
    out[t * 2 + o] = s;
}

extern "C" void kernel_launch(void* const* d_in, const int* in_sizes, int n_in,
                              void* d_out, int out_size, void* d_ws, size_t ws_size,
                              hipStream_t stream) {
    const float* x     = (const float*)d_in[0];
    const float* W_ih  = (const float*)d_in[1];
    const float* W_hh  = (const float*)d_in[2];
    const float* b_ih  = (const float*)d_in[3];
    const float* b_hh  = (const float*)d_in[4];
    const float* W_out = (const float*)d_in[5];
    const float* b_out = (const float*)d_in[6];
    float* out = (float*)d_out;

    // workspace layout: xp (T*256 floats) | hout (T*64 floats)  = 2.5 MB
    float* xp   = (float*)d_ws;
    float* hout = xp + (size_t)T_STEPS * NG;

    xproj_kernel<<<T_STEPS / XT, 256, 0, stream>>>(x, W_ih, b_ih, b_hh, xp);
    lstm_scan_kernel<<<1, 256, 0, stream>>>(W_hh, xp, hout);
    outproj_kernel<<<(T_STEPS * 2 + 255) / 256, 256, 0, stream>>>(hout, W_out, b_out, out);
}

// Round 6
// 846.308 us; speedup vs baseline: 1.6749x; 1.3226x over previous
//
#include <hip/hip_runtime.h>
#include <hip/hip_bf16.h>

// LSTM: T=2048, B=512, INPUT=42, HIDDEN=64. Output uses ONLY batch element 511
// (reference indexes lstm_out[:, -1, :]). Single-row recurrence: 2048
// sequential steps of a 256x64 matvec + activations on ONE block.
//
// History: R3 compiler sank weight loads (VGPR=44); R4 "memory" clobber made
// RA spill instead (VGPR=52, scratch reload = 1170 cyc/step); R5
// amdgpu_waves_per_eu(1,1) fixed residency (VGPR=132) but only -95us ->
// remaining cost is per-step latency chain. R6: __shfl_xor was lowering to
// ds_bpermute (LDS pipe, 2 dependent rounds) -> replace with quad_perm DPP
// adds (pure VALU); scalar v_fma -> v_pk_fma_f32 via float2 elementwise fma
// (halves FMA issue: 128 -> 64 cyc/step).

#define T_STEPS 2048
#define BATCH   512
#define NIN     42
#define NH      64
#define NG      256   // 4*NH
#define CH      8     // scan steps per chunk
#define NCHUNK  (T_STEPS / CH)
#define XT      16    // timesteps per xproj block

typedef float v2f __attribute__((ext_vector_type(2)));

// ---------------- Kernel 1: input projection for batch row 511 ----------------
__global__ __launch_bounds__(256) void xproj_kernel(
    const float* __restrict__ x, const float* __restrict__ W_ih,
    const float* __restrict__ b_ih, const float* __restrict__ b_hh,
    float* __restrict__ xp)
{
    const int g  = threadIdx.x;          // gate row 0..255
    const int t0 = blockIdx.x * XT;
    __shared__ float ws[NG * NIN];       // W_ih rows, packed [g][42]
    __shared__ float xs[XT][NIN];
    for (int i = threadIdx.x; i < NG * NIN; i += 256) ws[i] = W_ih[i];
    for (int i = threadIdx.x; i < XT * NIN; i += 256) {
        int tt = i / NIN, j = i % NIN;
        xs[tt][j] = x[((size_t)(t0 + tt) * BATCH + (BATCH - 1)) * NIN + j];
    }
    const float bias = b_ih[g] + b_hh[g];
    __syncthreads();
    const float* wr = &ws[g * NIN];
    for (int tt = 0; tt < XT; ++tt) {
        float s = bias;
#pragma unroll
        for (int i = 0; i < NIN; ++i) s += wr[i] * xs[tt][i];
        xp[(size_t)(t0 + tt) * NG + g] = s;
    }
}

// ---------------- Kernel 2: sequential LSTM scan (1 block, 256 threads) -------
// Barrier draining ONLY LDS ops (lgkmcnt); global loads/stores stay in flight.
__device__ __forceinline__ void wg_barrier_lgkm() {
    asm volatile("s_waitcnt lgkmcnt(0)\n\ts_barrier" ::: "memory");
}

__device__ __forceinline__ void pin2(v2f& v) {
    asm volatile("" : "+v"(v));
}

// xor-add within a quad via DPP quad_perm (pure VALU; no LDS pipe).
// xor1: perm [1,0,3,2] = 0xB1 ; xor2: perm [2,3,0,1] = 0x4E
template <int CTRL>
__device__ __forceinline__ float dpp_xadd(float v) {
    int s = __builtin_amdgcn_mov_dpp(__float_as_int(v), CTRL, 0xF, 0xF, true);
    return v + __int_as_float(s);
}

__device__ __forceinline__ float sigmoid_f(float x) {
    return __builtin_amdgcn_rcpf(1.f + __expf(-x));
}
__device__ __forceinline__ float tanh_f(float x) {
    return 1.f - 2.f * __builtin_amdgcn_rcpf(1.f + __expf(2.f * x));
}

__device__ __forceinline__ v2f fma2(v2f a, v2f b, v2f c) {
    return __builtin_elementwise_fma(a, b, c);   // -> v_pk_fma_f32
}

__global__ void
__attribute__((amdgpu_flat_work_group_size(256, 256), amdgpu_waves_per_eu(1, 1)))
lstm_scan_kernel(
    const float* __restrict__ W_hh, const float* __restrict__ xp,
    float* __restrict__ hout)
{
    const int lane = threadIdx.x;       // 0..255
    const int kc   = lane & 3;          // k-chunk (quad position)
    const int u    = lane >> 2;         // hidden unit

    __shared__ __align__(16) float hbuf[2][NH];        // h exchange (double buf)
    __shared__ __align__(16) float hstage[2][CH][NH];  // hout staging
    if (lane < NH) { hbuf[0][lane] = 0.f; hbuf[1][lane] = 0.f; }

    // Weights: W_hh[gate*64+u][kc*16 .. +16) as 8 v2f per gate = 64 VGPRs.
    const v2f* W0 = (const v2f*)(W_hh + (0 * NH + u) * NH + kc * 16);
    const v2f* W1 = (const v2f*)(W_hh + (1 * NH + u) * NH + kc * 16);
    const v2f* W2 = (const v2f*)(W_hh + (2 * NH + u) * NH + kc * 16);
    const v2f* W3 = (const v2f*)(W_hh + (3 * NH + u) * NH + kc * 16);
    v2f w0a=W0[0], w0b=W0[1], w0c=W0[2], w0d=W0[3], w0e=W0[4], w0f=W0[5], w0g=W0[6], w0h=W0[7];
    v2f w1a=W1[0], w1b=W1[1], w1c=W1[2], w1d=W1[3], w1e=W1[4], w1f=W1[5], w1g=W1[6], w1h=W1[7];
    v2f w2a=W2[0], w2b=W2[1], w2c=W2[2], w2d=W2[3], w2e=W2[4], w2f=W2[5], w2g=W2[6], w2h=W2[7];
    v2f w3a=W3[0], w3b=W3[1], w3c=W3[2], w3d=W3[3], w3e=W3[4], w3f=W3[5], w3g=W3[6], w3h=W3[7];
    pin2(w0a); pin2(w0b); pin2(w0c); pin2(w0d); pin2(w0e); pin2(w0f); pin2(w0g); pin2(w0h);
    pin2(w1a); pin2(w1b); pin2(w1c); pin2(w1d); pin2(w1e); pin2(w1f); pin2(w1g); pin2(w1h);
    pin2(w2a); pin2(w2b); pin2(w2c); pin2(w2d); pin2(w2e); pin2(w2f); pin2(w2g); pin2(w2h);
    pin2(w3a); pin2(w3b); pin2(w3c); pin2(w3d); pin2(w3e); pin2(w3f); pin2(w3g); pin2(w3h);

    float c = 0.f;
    const int seed_off = kc * NH + u;   // my xp column

    float xq[CH];
#pragma unroll
    for (int tt = 0; tt < CH; ++tt) xq[tt] = xp[tt * NG + seed_off];

    wg_barrier_lgkm();                  // hbuf zeros visible

    for (int ch = 0; ch < NCHUNK; ++ch) {
        float xn[CH];
        if (ch + 1 < NCHUNK) {
#pragma unroll
            for (int tt = 0; tt < CH; ++tt)
                xn[tt] = xp[(size_t)(ch + 1) * (CH * NG) + tt * NG + seed_off];
        }

#pragma unroll
        for (int tt = 0; tt < CH; ++tt) {
            const int p = tt & 1;
            const float4* hb = (const float4*)hbuf[p];
            float4 hv0 = hb[kc * 4 + 0];
            float4 hv1 = hb[kc * 4 + 1];
            float4 hv2 = hb[kc * 4 + 2];
            float4 hv3 = hb[kc * 4 + 3];
            v2f h0 = {hv0.x, hv0.y}, h1 = {hv0.z, hv0.w};
            v2f h2 = {hv1.x, hv1.y}, h3 = {hv1.z, hv1.w};
            v2f h4 = {hv2.x, hv2.y}, h5 = {hv2.z, hv2.w};
            v2f h6 = {hv3.x, hv3.y}, h7 = {hv3.z, hv3.w};

            v2f a0 = {(kc == 0) ? xq[tt] : 0.f, 0.f};
            v2f a1 = {(kc == 1) ? xq[tt] : 0.f, 0.f};
            v2f a2 = {(kc == 2) ? xq[tt] : 0.f, 0.f};
            v2f a3 = {(kc == 3) ? xq[tt] : 0.f, 0.f};

            a0 = fma2(w0a, h0, a0); a0 = fma2(w0b, h1, a0);
            a0 = fma2(w0c, h2, a0); a0 = fma2(w0d, h3, a0);
            a0 = fma2(w0e, h4, a0); a0 = fma2(w0f, h5, a0);
            a0 = fma2(w0g, h6, a0); a0 = fma2(w0h, h7, a0);
            a1 = fma2(w1a, h0, a1); a1 = fma2(w1b, h1, a1);
            a1 = fma2(w1c, h2, a1); a1 = fma2(w1d, h3, a1);
            a1 = fma2(w1e, h4, a1); a1 = fma2(w1f, h5, a1);
            a1 = fma2(w1g, h6, a1); a1 = fma2(w1h, h7, a1);
            a2 = fma2(w2a, h0, a2); a2 = fma2(w2b, h1, a2);
            a2 = fma2(w2c, h2, a2); a2 = fma2(w2d, h3, a2);
            a2 = fma2(w2e, h4, a2); a2 = fma2(w2f, h5, a2);
            a2 = fma2(w2g, h6, a2); a2 = fma2(w2h, h7, a2);
            a3 = fma2(w3a, h0, a3); a3 = fma2(w3b, h1, a3);
            a3 = fma2(w3c, h2, a3); a3 = fma2(w3d, h3, a3);
            a3 = fma2(w3e, h4, a3); a3 = fma2(w3f, h5, a3);
            a3 = fma2(w3g, h6, a3); a3 = fma2(w3h, h7, a3);

            float s0 = a0.x + a0.y;
            float s1 = a1.x + a1.y;
            float s2 = a2.x + a2.y;
            float s3 = a3.x + a3.y;

            // quad butterfly via DPP (xor1 then xor2) — pure VALU
            s0 = dpp_xadd<0xB1>(s0); s1 = dpp_xadd<0xB1>(s1);
            s2 = dpp_xadd<0xB1>(s2); s3 = dpp_xadd<0xB1>(s3);
            s0 = dpp_xadd<0x4E>(s0); s1 = dpp_xadd<0x4E>(s1);
            s2 = dpp_xadd<0x4E>(s2); s3 = dpp_xadd<0x4E>(s3);

            // gates i, f, g, o
            float i_ = sigmoid_f(s0);
            float f_ = sigmoid_f(s1);
            float g_ = tanh_f(s2);
            float o_ = sigmoid_f(s3);

            c = f_ * c + i_ * g_;
            float hn = o_ * tanh_f(c);

            if (kc == 0) {
                hbuf[1 - p][u] = hn;
                hstage[ch & 1][tt][u] = hn;
            }
            wg_barrier_lgkm();
        }

        // Flush chunk's h (8*64 floats), coalesced dwordx4, never awaited.
        if (lane < 128) {
            const float4 hv = *(const float4*)(&hstage[ch & 1][0][0] + lane * 4);
            *(float4*)(hout + (size_t)ch * (CH * NH) + lane * 4) = hv;
        }

#pragma unroll
        for (int tt = 0; tt < CH; ++tt) xq[tt] = xn[tt];
    }
}

// ---------------- Kernel 3: output projection out[t] = W_out @ h_t + b_out ----
__global__ __launch_bounds__(256) void outproj_kernel(
    const float* __restrict__ hout, const float* __restrict__ W_out,
    const float* __restrict__ b_out, float* __restrict__ out)
{
    int idx = blockIdx.x * blockDim.x + threadIdx.x;   // T*2
    if (idx >= T_STEPS * 2) return;
    int t = idx >> 1, o = idx & 1;
    const float* hr = hout + (size_t)t * NH;
    const float* wr = W_out + o * NH;
    float s = b_out[o];
#pragma unroll
    for (int j = 0; j < NH; ++j) s += hr[j] * wr[j];
    out[t * 2 + o] = s;
}

extern "C" void kernel_launch(void* const* d_in, const int* in_sizes, int n_in,
                              void* d_out, int out_size, void* d_ws, size_t ws_size,
                              hipStream_t stream) {
    const float* x     = (const float*)d_in[0];
    const float* W_ih  = (const float*)d_in[1];
    const float* W_hh  = (const float*)d_in[2];
    const float* b_ih  = (const float*)d_in[3];
    const float* b_hh  = (const float*)d_in[4];
    const float* W_out = (const float*)d_in[5];
    const float* b_out = (const float*)d_in[6];
    float* out = (float*)d_out;

    // workspace layout: xp (T*256 floats) | hout (T*64 floats)  = 2.5 MB
    float* xp   = (float*)d_ws;
    float* hout = xp + (size_t)T_STEPS * NG;

    xproj_kernel<<<T_STEPS / XT, 256, 0, stream>>>(x, W_ih, b_ih, b_hh, xp);
    lstm_scan_kernel<<<1, 256, 0, stream>>>(W_hh, xp, hout);
    outproj_kernel<<<(T_STEPS * 2 + 255) / 256, 256, 0, stream>>>(hout, W_out, b_out, out);
}